// Round 12
// baseline (2592.156 us; speedup 1.0000x reference)
//
#include <hip/hip_runtime.h>

#define N_NODES 50000
#define N_EDGES 800000
#define D_FEAT 96
#define HOP_NUM 4
#define OUT_STRIDE (HOP_NUM * D_FEAT)
#define SCAN_B 256
#define NBLK_SCAN ((N_NODES + SCAN_B - 1) / SCAN_B)  // 196
#define EB_BLOCKS ((N_EDGES + 255) / 256)            // 3125
#define F2B_VEC (N_NODES * D_FEAT / 4)               // 1.2M float4s

#define GROUP 24            // one lane per ushort4 chunk of a 96-ch row
#define GPB 8               // groups per block
#define HOP_BLOCK (GROUP * GPB)  // 192 threads = exactly 3 waves

#define NREG 8
#define REG_NODES ((N_NODES + NREG - 1) / NREG)      // 6250
#define NXCD 8
#define NBIN (NREG * NXCD)                           // 64
#define BIN_CAP 16384                                // mean fill 12.5K, huge margin
#define OVF_CAP 65536
#define RB 64                                        // blocks per region in phase 2

typedef float f32x4 __attribute__((ext_vector_type(4)));

__device__ __forceinline__ unsigned short f2bf(float x) {
    union { float f; unsigned u; } c; c.f = x;
    unsigned r = (c.u + 0x7FFFu + ((c.u >> 16) & 1u)) >> 16;  // RNE
    return (unsigned short)r;
}
__device__ __forceinline__ float bf2f(unsigned short b) {
    union { unsigned u; float f; } c; c.u = ((unsigned)b) << 16;
    return c.f;
}

__device__ __forceinline__ long long pack_st(int s, int t) {
    return ((long long)t << 32) | (unsigned)s;
}

// ---------- CSR build (once per launch) ----------

// zero deg + bin cursors (bcur[NBIN] = overflow cursor at index NBIN)
__global__ void zero_kernel(int* __restrict__ deg, int* __restrict__ bcur) {
    int i = blockIdx.x * blockDim.x + threadIdx.x;
    if (i < N_NODES) deg[i] = 0;
    if (i <= NBIN) bcur[i] = 0;
}

// Phase 1: degree histogram + bin edges by (dst-region, blockIdx%8).
// Appends within a bin are sequential and (assuming round-robin block->XCD)
// single-XCD, so write-back lines fill completely.
__global__ void bin_hist_kernel(const int* __restrict__ src, const int* __restrict__ dst,
                                int* __restrict__ deg, int* __restrict__ bcur,
                                long long* __restrict__ bins, long long* __restrict__ ovf) {
    int e = blockIdx.x * blockDim.x + threadIdx.x;
    if (e >= N_EDGES) return;
    int t = __builtin_nontemporal_load(&dst[e]);
    int s = __builtin_nontemporal_load(&src[e]);
    atomicAdd(&deg[t], 1);
    int b = (t / REG_NODES) * NXCD + (blockIdx.x & (NXCD - 1));
    int p = atomicAdd(&bcur[b], 1);
    if (p < BIN_CAP) {
        __builtin_nontemporal_store(pack_st(s, t), &bins[(long long)b * BIN_CAP + p]);
    } else {
        int q = atomicAdd(&bcur[NBIN], 1);
        if (q < OVF_CAP) ovf[q] = pack_st(s, t);
    }
}

// Phase A: per-block exclusive scan of deg into off (block-local), totals -> partials.
__global__ void scanA_kernel(const int* __restrict__ deg, int* __restrict__ off,
                             int* __restrict__ partials) {
    int i = blockIdx.x * SCAN_B + threadIdx.x;
    int v = (i < N_NODES) ? deg[i] : 0;
    int lane = threadIdx.x & 63;
    int wid  = threadIdx.x >> 6;
    int x = v;
    #pragma unroll
    for (int o = 1; o < 64; o <<= 1) {
        int y = __shfl_up(x, o, 64);
        if (lane >= o) x += y;
    }
    __shared__ int wtot[SCAN_B / 64];
    if (lane == 63) wtot[wid] = x;
    __syncthreads();
    int wbase = 0;
    #pragma unroll
    for (int w = 0; w < SCAN_B / 64; ++w) wbase += (w < wid) ? wtot[w] : 0;
    if (i < N_NODES) off[i] = wbase + x - v;
    if (threadIdx.x == SCAN_B - 1) partials[blockIdx.x] = wbase + x;
}

// Phase B: single block scans the 196 partials (exclusive, in place).
__global__ void scanB_kernel(int* __restrict__ partials) {
    int tid = threadIdx.x;  // 256 threads
    int v = (tid < NBLK_SCAN) ? partials[tid] : 0;
    int lane = tid & 63;
    int wid  = tid >> 6;
    int x = v;
    #pragma unroll
    for (int o = 1; o < 64; o <<= 1) {
        int y = __shfl_up(x, o, 64);
        if (lane >= o) x += y;
    }
    __shared__ int wtot[SCAN_B / 64];
    if (lane == 63) wtot[wid] = x;
    __syncthreads();
    int wbase = 0;
    #pragma unroll
    for (int w = 0; w < SCAN_B / 64; ++w) wbase += (w < wid) ? wtot[w] : 0;
    if (tid < NBLK_SCAN) partials[tid] = wbase + x - v;
}

// Phase C: add block bases -> GLOBAL offsets; zero the scatter cursor; off[N] = E.
__global__ void scanC_kernel(int* __restrict__ off, const int* __restrict__ partials,
                             int* __restrict__ cursor) {
    int i = blockIdx.x * SCAN_B + threadIdx.x;
    if (i < N_NODES) {
        off[i] += partials[blockIdx.x];
        cursor[i] = 0;
    }
    if (i == 0) off[N_NODES] = N_EDGES;
}

// Phase 2: blocks with blockIdx%8 == r drain region r's 8 bins into the CSR.
// Region r's cursor slice (25 KB) and output window (~400 KB) stay in one XCD's L2.
__global__ void scatter2_kernel(const long long* __restrict__ bins, const int* __restrict__ bcur,
                                const long long* __restrict__ ovf,
                                const int* __restrict__ off, int* __restrict__ cursor,
                                int* __restrict__ ssrc) {
    int r  = blockIdx.x & (NXCD - 1);
    int rb = blockIdx.x >> 3;  // 0..RB-1
    for (int x = 0; x < NXCD; ++x) {
        int b = r * NXCD + x;
        int cnt = min(bcur[b], BIN_CAP);
        for (int i = rb * blockDim.x + threadIdx.x; i < cnt; i += RB * blockDim.x) {
            long long pr = __builtin_nontemporal_load(&bins[(long long)b * BIN_CAP + i]);
            int s = (int)(pr & 0xFFFFFFFFLL);
            int t = (int)(pr >> 32);
            int p = atomicAdd(&cursor[t], 1);
            ssrc[off[t] + p] = s;
        }
    }
    int oc = min(bcur[NBIN], OVF_CAP);
    for (int i = rb * blockDim.x + threadIdx.x; i < oc; i += RB * blockDim.x) {
        long long pr = ovf[i];
        int s = (int)(pr & 0xFFFFFFFFLL);
        int t = (int)(pr >> 32);
        if (t / REG_NODES == r) {
            int p = atomicAdd(&cursor[t], 1);
            ssrc[off[t] + p] = s;
        }
    }
}

// seed: f32 features -> bf16 table
__global__ void f32_to_bf16_kernel(const float* __restrict__ in, unsigned short* __restrict__ out) {
    int i = blockIdx.x * blockDim.x + threadIdx.x;
    if (i >= F2B_VEC) return;
    float4 v = ((const float4*)in)[i];
    ushort4 o;
    o.x = f2bf(v.x); o.y = f2bf(v.y); o.z = f2bf(v.z); o.w = f2bf(v.w);
    ((ushort4*)out)[i] = o;
}

// ---------- fused per-hop SpMM + residual blend (bf16 gather table) ----------
__global__ void __launch_bounds__(HOP_BLOCK)
spmm_gather_kernel(const unsigned short* __restrict__ tab,
                   const int* __restrict__ off,
                   const int* __restrict__ ssrc,
                   const float* __restrict__ dn,
                   const float* __restrict__ lr, int hop,
                   float* __restrict__ out,
                   unsigned short* __restrict__ tab_next) {
    int t = blockIdx.x * HOP_BLOCK + threadIdx.x;
    int gid = t / GROUP;
    int lane = t % GROUP;
    if (gid >= N_NODES) return;
    int beg = off[gid];
    int end = off[gid + 1];
    float dnt = dn[gid];

    float4 acc = make_float4(0.f, 0.f, 0.f, 0.f);
    int k = beg;
    for (; k + 4 <= end; k += 4) {
        int s0 = ssrc[k];
        int s1 = ssrc[k + 1];
        int s2 = ssrc[k + 2];
        int s3 = ssrc[k + 3];
        float w0 = dn[s0] * dnt;
        float w1 = dn[s1] * dnt;
        float w2 = dn[s2] * dnt;
        float w3 = dn[s3] * dnt;
        ushort4 u0 = ((const ushort4*)(tab + (long long)s0 * D_FEAT))[lane];
        ushort4 u1 = ((const ushort4*)(tab + (long long)s1 * D_FEAT))[lane];
        ushort4 u2 = ((const ushort4*)(tab + (long long)s2 * D_FEAT))[lane];
        ushort4 u3 = ((const ushort4*)(tab + (long long)s3 * D_FEAT))[lane];
        acc.x = fmaf(bf2f(u0.x), w0, fmaf(bf2f(u1.x), w1, fmaf(bf2f(u2.x), w2, fmaf(bf2f(u3.x), w3, acc.x))));
        acc.y = fmaf(bf2f(u0.y), w0, fmaf(bf2f(u1.y), w1, fmaf(bf2f(u2.y), w2, fmaf(bf2f(u3.y), w3, acc.y))));
        acc.z = fmaf(bf2f(u0.z), w0, fmaf(bf2f(u1.z), w1, fmaf(bf2f(u2.z), w2, fmaf(bf2f(u3.z), w3, acc.z))));
        acc.w = fmaf(bf2f(u0.w), w0, fmaf(bf2f(u1.w), w1, fmaf(bf2f(u2.w), w2, fmaf(bf2f(u3.w), w3, acc.w))));
    }
    for (; k < end; ++k) {
        int s = ssrc[k];
        float w = dn[s] * dnt;
        ushort4 u = ((const ushort4*)(tab + (long long)s * D_FEAT))[lane];
        acc.x = fmaf(bf2f(u.x), w, acc.x);
        acc.y = fmaf(bf2f(u.y), w, acc.y);
        acc.z = fmaf(bf2f(u.z), w, acc.z);
        acc.w = fmaf(bf2f(u.w), w, acc.w);
    }

    float r = lr[hop];
    ushort4 pu = ((const ushort4*)(tab + (long long)gid * D_FEAT))[lane];
    f32x4 o;
    o.x = acc.x * r + (1.0f - r) * bf2f(pu.x);
    o.y = acc.y * r + (1.0f - r) * bf2f(pu.y);
    o.z = acc.z * r + (1.0f - r) * bf2f(pu.z);
    o.w = acc.w * r + (1.0f - r) * bf2f(pu.w);
    __builtin_nontemporal_store(o, (f32x4*)(out + (long long)gid * OUT_STRIDE) + lane);
    if (tab_next) {
        ushort4 ov;
        ov.x = f2bf(o.x); ov.y = f2bf(o.y); ov.z = f2bf(o.z); ov.w = f2bf(o.w);
        ((ushort4*)(tab_next + (long long)gid * D_FEAT))[lane] = ov;
    }
}

extern "C" void kernel_launch(void* const* d_in, const int* in_sizes, int n_in,
                              void* d_out, int out_size, void* d_ws, size_t ws_size,
                              hipStream_t stream) {
    const float* h   = (const float*)d_in[0];
    const float* dn  = (const float*)d_in[1];
    const int*   src = (const int*)d_in[2];
    const int*   dst = (const int*)d_in[3];
    const float* lr  = (const float*)d_in[4];
    float* out = (float*)d_out;

    // workspace carve-up (8/16B-aligned chunks first)
    char* base = (char*)d_ws;
    long long* bins = (long long*)base;           base += (size_t)NBIN * BIN_CAP * sizeof(long long);  // 8 MB
    long long* ovf  = (long long*)base;           base += (size_t)OVF_CAP * sizeof(long long);         // 512 KB
    unsigned short* tabA = (unsigned short*)base; base += (size_t)N_NODES * D_FEAT * sizeof(unsigned short);
    unsigned short* tabB = (unsigned short*)base; base += (size_t)N_NODES * D_FEAT * sizeof(unsigned short);
    int* ssrc     = (int*)base;                   base += (size_t)N_EDGES * sizeof(int);
    int* off      = (int*)base;                   base += (N_NODES + 1) * sizeof(int);
    int* deg      = (int*)base;                   base += N_NODES * sizeof(int);
    int* cursor   = (int*)base;                   base += N_NODES * sizeof(int);
    int* partials = (int*)base;                   base += NBLK_SCAN * sizeof(int);
    int* bcur     = (int*)base;                   base += (NBIN + 1) * sizeof(int);

    zero_kernel<<<NBLK_SCAN, SCAN_B, 0, stream>>>(deg, bcur);
    bin_hist_kernel<<<EB_BLOCKS, 256, 0, stream>>>(src, dst, deg, bcur, bins, ovf);
    scanA_kernel<<<NBLK_SCAN, SCAN_B, 0, stream>>>(deg, off, partials);
    scanB_kernel<<<1, SCAN_B, 0, stream>>>(partials);
    scanC_kernel<<<NBLK_SCAN, SCAN_B, 0, stream>>>(off, partials, cursor);
    scatter2_kernel<<<NXCD * RB, 256, 0, stream>>>(bins, bcur, ovf, off, cursor, ssrc);
    f32_to_bf16_kernel<<<(F2B_VEC + 255) / 256, 256, 0, stream>>>(h, tabA);

    // 4 fused hops (bf16 ping-pong tables)
    const int HB = (N_NODES + GPB - 1) / GPB;  // 6250 blocks of 192 threads
    unsigned short* cur = tabA;
    unsigned short* nxt = tabB;
    for (int hop = 0; hop < HOP_NUM; ++hop) {
        unsigned short* wr = (hop == HOP_NUM - 1) ? (unsigned short*)nullptr : nxt;
        spmm_gather_kernel<<<HB, HOP_BLOCK, 0, stream>>>(cur, off, ssrc, dn, lr, hop,
                                                         out + hop * D_FEAT, wr);
        unsigned short* t = cur; cur = nxt; nxt = t;
    }
}

// Round 14
// 747.414 us; speedup vs baseline: 3.4682x; 3.4682x over previous
//
#include <hip/hip_runtime.h>

#define N_NODES 50000
#define N_EDGES 800000
#define D_FEAT 96
#define HOP_NUM 4
#define OUT_STRIDE (HOP_NUM * D_FEAT)
#define SCAN_B 256
#define NBLK_SCAN ((N_NODES + SCAN_B - 1) / SCAN_B)  // 196
#define EB_BLOCKS ((N_EDGES + 255) / 256)            // 3125
#define F2B_VEC (N_NODES * D_FEAT / 4)               // 1.2M float4s

#define SPLIT 4
#define CH_Q (D_FEAT / SPLIT)                        // 24 channels per quarter
#define U4_Q (CH_Q / 4)                              // 6 ushort4 per quarter
#define NODE_BLOCKS ((N_NODES + 255) / 256)          // 196 (even)
#define HOP_GRID (NODE_BLOCKS / 2 * 8)               // 784 blocks

typedef float f32x4 __attribute__((ext_vector_type(4)));

__device__ __forceinline__ unsigned short f2bf(float x) {
    union { float f; unsigned u; } c; c.f = x;
    unsigned r = (c.u + 0x7FFFu + ((c.u >> 16) & 1u)) >> 16;  // RNE
    return (unsigned short)r;
}
__device__ __forceinline__ float bf2f(unsigned short b) {
    union { unsigned u; float f; } c; c.u = ((unsigned)b) << 16;
    return c.f;
}

// ---------- CSR build (round-9 form: proven ~219 us structure) ----------

__global__ void zero_deg_kernel(int* __restrict__ deg) {
    int i = blockIdx.x * blockDim.x + threadIdx.x;
    if (i < N_NODES) deg[i] = 0;
}

__global__ void hist_kernel(const int* __restrict__ dst, int* __restrict__ deg) {
    int e = blockIdx.x * blockDim.x + threadIdx.x;
    if (e >= N_EDGES) return;
    atomicAdd(&deg[dst[e]], 1);
}

__global__ void scanA_kernel(const int* __restrict__ deg, int* __restrict__ off,
                             int* __restrict__ partials) {
    int i = blockIdx.x * SCAN_B + threadIdx.x;
    int v = (i < N_NODES) ? deg[i] : 0;
    int lane = threadIdx.x & 63;
    int wid  = threadIdx.x >> 6;
    int x = v;
    #pragma unroll
    for (int o = 1; o < 64; o <<= 1) {
        int y = __shfl_up(x, o, 64);
        if (lane >= o) x += y;
    }
    __shared__ int wtot[SCAN_B / 64];
    if (lane == 63) wtot[wid] = x;
    __syncthreads();
    int wbase = 0;
    #pragma unroll
    for (int w = 0; w < SCAN_B / 64; ++w) wbase += (w < wid) ? wtot[w] : 0;
    if (i < N_NODES) off[i] = wbase + x - v;
    if (threadIdx.x == SCAN_B - 1) partials[blockIdx.x] = wbase + x;
}

__global__ void scanB_kernel(int* __restrict__ partials) {
    int tid = threadIdx.x;  // 256 threads
    int v = (tid < NBLK_SCAN) ? partials[tid] : 0;
    int lane = tid & 63;
    int wid  = tid >> 6;
    int x = v;
    #pragma unroll
    for (int o = 1; o < 64; o <<= 1) {
        int y = __shfl_up(x, o, 64);
        if (lane >= o) x += y;
    }
    __shared__ int wtot[SCAN_B / 64];
    if (lane == 63) wtot[wid] = x;
    __syncthreads();
    int wbase = 0;
    #pragma unroll
    for (int w = 0; w < SCAN_B / 64; ++w) wbase += (w < wid) ? wtot[w] : 0;
    if (tid < NBLK_SCAN) partials[tid] = wbase + x - v;
}

__global__ void scanC_kernel(int* __restrict__ off, const int* __restrict__ partials,
                             int* __restrict__ cursor) {
    int i = blockIdx.x * SCAN_B + threadIdx.x;
    if (i < N_NODES) {
        off[i] += partials[blockIdx.x];
        cursor[i] = 0;
    }
    if (i == 0) off[N_NODES] = N_EDGES;
}

__global__ void scatter_kernel(const int* __restrict__ src, const int* __restrict__ dst,
                               const int* __restrict__ off, int* __restrict__ cursor,
                               int* __restrict__ ssrc) {
    int e = blockIdx.x * blockDim.x + threadIdx.x;
    if (e >= N_EDGES) return;
    int t = dst[e];
    int s = src[e];
    int p = atomicAdd(&cursor[t], 1);
    ssrc[off[t] + p] = s;
}

__global__ void f32_to_bf16_kernel(const float* __restrict__ in, unsigned short* __restrict__ out) {
    int i = blockIdx.x * blockDim.x + threadIdx.x;
    if (i >= F2B_VEC) return;
    float4 v = ((const float4*)in)[i];
    ushort4 o;
    o.x = f2bf(v.x); o.y = f2bf(v.y); o.z = f2bf(v.z); o.w = f2bf(v.w);
    ((ushort4*)out)[i] = o;
}

// ---------- per-hop SpMM + residual blend, channel-split across XCDs ----------
// Quarter q = (blockIdx%8)>>1 -> XCD pair under round-robin mapping.
// One thread per dst node; each thread accumulates its quarter's 24 channels.
// Per-XCD working slice = 2.4 MB -> L2-resident; edges re-streamed with NT loads.
// `out` arrives pre-offset by hop*D_FEAT.
__global__ void __launch_bounds__(256)
spmm_hop_kernel(const unsigned short* __restrict__ tab,
                const int* __restrict__ off,
                const int* __restrict__ ssrc,
                const float* __restrict__ dn,
                const float* __restrict__ lr, int hop,
                float* __restrict__ out,
                unsigned short* __restrict__ tab_next) {
    int q  = (blockIdx.x & 7) >> 1;                        // channel quarter
    int nb = ((blockIdx.x >> 3) << 1) | (blockIdx.x & 1);  // node block 0..195
    int n  = nb * 256 + threadIdx.x;
    if (n >= N_NODES) return;
    int beg = off[n];
    int end = off[n + 1];
    float dnt = dn[n];

    float acc[CH_Q];
    #pragma unroll
    for (int c = 0; c < CH_Q; ++c) acc[c] = 0.f;

    for (int k = beg; k < end; ++k) {
        int s = __builtin_nontemporal_load(&ssrc[k]);
        float w = dn[s] * dnt;
        const ushort4* r4 = (const ushort4*)(tab + (size_t)s * D_FEAT) + q * U4_Q;
        #pragma unroll
        for (int c = 0; c < U4_Q; ++c) {
            ushort4 u = r4[c];
            acc[4 * c + 0] = fmaf(bf2f(u.x), w, acc[4 * c + 0]);
            acc[4 * c + 1] = fmaf(bf2f(u.y), w, acc[4 * c + 1]);
            acc[4 * c + 2] = fmaf(bf2f(u.z), w, acc[4 * c + 2]);
            acc[4 * c + 3] = fmaf(bf2f(u.w), w, acc[4 * c + 3]);
        }
    }

    float r = lr[hop];
    const ushort4* prow = (const ushort4*)(tab + (size_t)n * D_FEAT) + q * U4_Q;
    f32x4* orow = (f32x4*)(out + (size_t)n * OUT_STRIDE) + q * U4_Q;
    ushort4* trow = tab_next ? ((ushort4*)(tab_next + (size_t)n * D_FEAT) + q * U4_Q) : nullptr;
    #pragma unroll
    for (int c = 0; c < U4_Q; ++c) {
        ushort4 pu = prow[c];
        f32x4 o;
        o.x = acc[4 * c + 0] * r + (1.0f - r) * bf2f(pu.x);
        o.y = acc[4 * c + 1] * r + (1.0f - r) * bf2f(pu.y);
        o.z = acc[4 * c + 2] * r + (1.0f - r) * bf2f(pu.z);
        o.w = acc[4 * c + 3] * r + (1.0f - r) * bf2f(pu.w);
        __builtin_nontemporal_store(o, orow + c);  // write-once f32 output
        if (trow) {
            ushort4 ov;
            ov.x = f2bf(o.x); ov.y = f2bf(o.y); ov.z = f2bf(o.z); ov.w = f2bf(o.w);
            trow[c] = ov;  // NOT nontemporal: same XCD pair reads it next hop
        }
    }
}

extern "C" void kernel_launch(void* const* d_in, const int* in_sizes, int n_in,
                              void* d_out, int out_size, void* d_ws, size_t ws_size,
                              hipStream_t stream) {
    const float* h   = (const float*)d_in[0];
    const float* dn  = (const float*)d_in[1];
    const int*   src = (const int*)d_in[2];
    const int*   dst = (const int*)d_in[3];
    const float* lr  = (const float*)d_in[4];
    float* out = (float*)d_out;

    // workspace carve-up (16B-aligned chunks first)
    char* base = (char*)d_ws;
    unsigned short* tabA = (unsigned short*)base; base += (size_t)N_NODES * D_FEAT * sizeof(unsigned short);
    unsigned short* tabB = (unsigned short*)base; base += (size_t)N_NODES * D_FEAT * sizeof(unsigned short);
    int* ssrc     = (int*)base;                   base += (size_t)N_EDGES * sizeof(int);
    int* off      = (int*)base;                   base += (N_NODES + 1) * sizeof(int);
    int* deg      = (int*)base;                   base += N_NODES * sizeof(int);
    int* cursor   = (int*)base;                   base += N_NODES * sizeof(int);
    int* partials = (int*)base;                   base += NBLK_SCAN * sizeof(int);

    zero_deg_kernel<<<NBLK_SCAN, SCAN_B, 0, stream>>>(deg);
    hist_kernel<<<EB_BLOCKS, 256, 0, stream>>>(dst, deg);
    scanA_kernel<<<NBLK_SCAN, SCAN_B, 0, stream>>>(deg, off, partials);
    scanB_kernel<<<1, SCAN_B, 0, stream>>>(partials);
    scanC_kernel<<<NBLK_SCAN, SCAN_B, 0, stream>>>(off, partials, cursor);
    scatter_kernel<<<EB_BLOCKS, 256, 0, stream>>>(src, dst, off, cursor, ssrc);
    f32_to_bf16_kernel<<<(F2B_VEC + 255) / 256, 256, 0, stream>>>(h, tabA);

    // 4 hops (bf16 ping-pong tables), channel-split grid; out pre-offset per hop
    unsigned short* cur = tabA;
    unsigned short* nxt = tabB;
    for (int hop = 0; hop < HOP_NUM; ++hop) {
        unsigned short* wr = (hop == HOP_NUM - 1) ? (unsigned short*)nullptr : nxt;
        spmm_hop_kernel<<<HOP_GRID, 256, 0, stream>>>(cur, off, ssrc, dn, lr, hop,
                                                      out + hop * D_FEAT, wr);
        unsigned short* t = cur; cur = nxt; nxt = t;
    }
}